// Round 16
// baseline (193.001 us; speedup 1.0000x reference)
//
#include <hip/hip_runtime.h>
#include <hip/hip_bf16.h>
#include <cstdint>
#include <cstddef>

// ---------------------------------------------------------------------------
// LlamaAttention forward: out = Attn(RoPE(x@wq), RoPE(x@wk), x@wv) @ wo
// B=2 T=2048 C=2048 NH=32 NKV=8 D=64, causal, GQA rep=4, scale=1/8.
// R16: GEMM K-loops -> 4-buffer BK=32 half-tile pipeline with counted vmcnt
// (T3+T4): stage(h+3); ds_read(h); MFMA; lgkm0; vmcnt(8); barrier. One
// barrier per half-tile (was 4/tile), loads in flight 3 half-tiles (~900cy
// >= HBM latency). Swizzle: chunk ^= row&3 (4 chunks/row), both sides.
// QKV 256x192 (B staged as 256 rows, 192-255 junk, never read).
// Out-proj 256x128. Epilogues/attn/prep unchanged from R15.
// ---------------------------------------------------------------------------

using bf16 = __hip_bfloat16;
using f32x4  = __attribute__((ext_vector_type(4))) float;
using f32x16 = __attribute__((ext_vector_type(16))) float;
using short8 = __attribute__((ext_vector_type(8))) short;
using u32x4  = __attribute__((ext_vector_type(4))) unsigned int;

typedef __attribute__((address_space(1))) const void* gp1_t;
typedef __attribute__((address_space(3))) void*       lp3_t;

#define GLOAD_LDS16(g, l)                                                     \
  __builtin_amdgcn_global_load_lds((gp1_t)(const void*)(g), (lp3_t)(void*)(l), 16, 0, 0)

#define MFMA16(a, b, c) __builtin_amdgcn_mfma_f32_16x16x32_bf16(a, b, c, 0, 0, 0)
#define MFMA32(a, b, c) __builtin_amdgcn_mfma_f32_32x32x16_bf16(a, b, c, 0, 0, 0)

static constexpr int Bd  = 2;
static constexpr int Td  = 2048;
static constexpr int Cd  = 2048;
static constexpr int NH  = 32;
static constexpr int NKV = 8;
static constexpr int HD  = 64;
static constexpr int Md  = Bd * Td;     // 4096 rows

__device__ inline float bf2f(unsigned short u) {
  union { unsigned int i; float f; } v; v.i = ((unsigned int)u) << 16; return v.f;
}
__device__ inline unsigned short f2bfbits(float f) {
  union { float f; unsigned int u; } v; v.f = f;
  unsigned int r = v.u + 0x7fffu + ((v.u >> 16) & 1u);   // RNE
  return (unsigned short)(r >> 16);
}
__device__ inline unsigned int pkbf(float a, float b) {   // lo=bf16(a), hi=bf16(b)
  unsigned int r;
  asm("v_cvt_pk_bf16_f32 %0, %1, %2" : "=v"(r) : "v"(a), "v"(b));
  return r;
}
// v_permlane32_swap_b32 d, s:  after: d = {d.lo, s.lo}, s = {d.hi, s.hi}.
__device__ inline void plswapf(float& a, float& b) {
  asm("v_permlane32_swap_b32 %0, %1" : "+v"(a), "+v"(b));
}
__device__ inline void plswapu(unsigned int& a, unsigned int& b) {
  asm("v_permlane32_swap_b32 %0, %1" : "+v"(a), "+v"(b));
}
__device__ inline float hmax16(const f32x16& v) {
  float a0 = fmaxf(v[0], v[1]),   a1 = fmaxf(v[2], v[3]);
  float a2 = fmaxf(v[4], v[5]),   a3 = fmaxf(v[6], v[7]);
  float a4 = fmaxf(v[8], v[9]),   a5 = fmaxf(v[10], v[11]);
  float a6 = fmaxf(v[12], v[13]), a7 = fmaxf(v[14], v[15]);
  float b0 = fmaxf(a0, a1), b1 = fmaxf(a2, a3);
  float b2 = fmaxf(a4, a5), b3 = fmaxf(a6, a7);
  return fmaxf(fmaxf(b0, b1), fmaxf(b2, b3));
}
__device__ inline float hsum16(const f32x16& v) {
  float a0 = v[0]+v[1],   a1 = v[2]+v[3],   a2 = v[4]+v[5],   a3 = v[6]+v[7];
  float a4 = v[8]+v[9],   a5 = v[10]+v[11], a6 = v[12]+v[13], a7 = v[14]+v[15];
  float b0 = a0+a1, b1 = a2+a3, b2 = a4+a5, b3 = a6+a7;
  return (b0+b1)+(b2+b3);
}

// ---------------- prep1: x->bf16 + wq/wk/wv (+wo) fp32->bf16^T -------------
__global__ __launch_bounds__(256) void prep1_kernel(const float* __restrict__ x,
                                                    const float* __restrict__ wq,
                                                    const float* __restrict__ wk,
                                                    const float* __restrict__ wv,
                                                    const float* __restrict__ wo,
                                                    bf16* __restrict__ xb,
                                                    bf16* __restrict__ w1,
                                                    bf16* __restrict__ woT) {
  __shared__ float tile[32][33];
  int bid = blockIdx.x, tid = threadIdx.x;
  if (bid < 8192) {
    int i = bid * 256 + tid;
    float4 v = ((const float4*)x)[i];
    ushort4 o;
    o.x = f2bfbits(v.x); o.y = f2bfbits(v.y); o.z = f2bfbits(v.z); o.w = f2bfbits(v.w);
    ((ushort4*)xb)[i] = o;
    return;
  }
  const float* in; bf16* out; int Cc, bx, by;
  if (bid < 12288)      { int l = bid - 8192;  in = wq; out = w1;                        Cc = 2048; bx = l & 63; by = l >> 6; }
  else if (bid < 13312) { int l = bid - 12288; in = wk; out = w1 + (size_t)2048 * 2048;  Cc = 512;  bx = l & 15; by = l >> 4; }
  else if (bid < 14336) { int l = bid - 13312; in = wv; out = w1 + (size_t)2560 * 2048;  Cc = 512;  bx = l & 15; by = l >> 4; }
  else                  { int l = bid - 14336; in = wo; out = woT;                       Cc = 2048; bx = l & 63; by = l >> 6; }
  int tx = tid & 31, ty = tid >> 5;
  int col = bx * 32 + tx;
#pragma unroll
  for (int i = 0; i < 4; ++i) {
    int row = by * 32 + ty + i * 8;
    tile[ty + i * 8][tx] = in[(size_t)row * Cc + col];
  }
  __syncthreads();
#pragma unroll
  for (int i = 0; i < 4; ++i) {
    int orow = bx * 32 + ty + i * 8;
    int ocol = by * 32 + tx;
    out[(size_t)orow * 2048 + ocol] = __float2bfloat16(tile[tx][ty + i * 8]);
  }
}

// ---------------- fp32 [R][Cc] -> bf16 transpose [Cc][R] (fallback wo) -----
__global__ __launch_bounds__(256) void transpose_f2b(const float* __restrict__ in,
                                                     bf16* __restrict__ out,
                                                     int R, int Cc) {
  __shared__ float tile[32][33];
  int tx = threadIdx.x & 31, ty = threadIdx.x >> 5;
  int bx = blockIdx.x, by = blockIdx.y;
  int col = bx * 32 + tx;
#pragma unroll
  for (int i = 0; i < 4; ++i) {
    int row = by * 32 + ty + i * 8;
    tile[ty + i * 8][tx] = in[(size_t)row * Cc + col];
  }
  __syncthreads();
#pragma unroll
  for (int i = 0; i < 4; ++i) {
    int orow = bx * 32 + ty + i * 8;
    int ocol = by * 32 + tx;
    out[(size_t)orow * R + ocol] = __float2bfloat16(tile[tx][ty + i * 8]);
  }
}

// ---------------- QKV GEMM: 256x192, 8 waves, 4-buf BK=32 pipeline ---------
// grid (16,16) = 256 blocks (full chip). Per-wave C = 128x48 (acc 8x3).
// LDS: A 4 x 16KB @0 | B 4 x 16KB @65536 (B rows 192-255 junk). Swizzle:
// LDS[row][c] = global[row][c ^ (row&3)], 16B chunks, 64B rows.
// Loop: stage(h+3); ds_read(h); 24 MFMA; lgkm0; vmcnt(8); barrier.
// Fused epilogue: RoPE Q (prescaled)/K; V^T via LDS transpose.
__global__ __launch_bounds__(512, 2) void gemm_qkv(const bf16* __restrict__ A,
                                                   const bf16* __restrict__ Bt,
                                                   void* __restrict__ Cp,
                                                   int M, int N, int K) {
  __shared__ __align__(16) char lds[131072];
  int tid = threadIdx.x;
  int w = tid >> 6, lane = tid & 63;
  int lr = lane & 15, lg = lane >> 4;
  int m0 = blockIdx.x * 256, n0 = blockIdx.y * 192;
  int wr = w >> 2, wc = w & 3;                 // 2M x 4N wave grid
  f32x4 acc[8][3] = {};

  size_t Kb = (size_t)K * 2;
  int srw = lane >> 2;                         // row-in-16 (0..15)
  int swc = ((lane & 3) ^ (srw & 3)) << 4;     // inverse-swizzled src chunk
  const char* AsrcT = (const char*)A + (size_t)(m0 + w * 16 + srw) * Kb + swc;
  const char* BsrcT = (const char*)Bt + (size_t)(n0 + w * 16 + srw) * Kb + swc;
  char* AldW = lds + w * 1024;
  char* BldW = lds + 65536 + w * 1024;

#define GSTAGE(ht) do {                                                       \
    int _b = (ht) & 3; size_t _k = (size_t)(ht) * 64;                         \
    GLOAD_LDS16(AsrcT + _k,                      AldW + _b * 16384);          \
    GLOAD_LDS16(AsrcT + (size_t)128 * Kb + _k,   AldW + _b * 16384 + 8192);   \
    GLOAD_LDS16(BsrcT + _k,                      BldW + _b * 16384);          \
    GLOAD_LDS16(BsrcT + (size_t)128 * Kb + _k,   BldW + _b * 16384 + 8192);   \
  } while (0)

  int nht = K >> 5;                            // 64 half-tiles
  GSTAGE(0); GSTAGE(1); GSTAGE(2);
  asm volatile("s_waitcnt vmcnt(8)" ::: "memory");
  __builtin_amdgcn_s_barrier();

  int cbase = (lg ^ (lr & 3)) << 4;
  for (int ht = 0; ht < nht; ++ht) {
    int buf = ht & 3;
    if (ht + 3 < nht) GSTAGE(ht + 3);
    const char* Ab = lds + buf * 16384;
    const char* Bb = lds + 65536 + buf * 16384;
    short8 af[8], bfr[3];
#pragma unroll
    for (int f = 0; f < 8; ++f)
      af[f] = *(const short8*)(Ab + (size_t)(wr * 128 + f * 16 + lr) * 64 + cbase);
#pragma unroll
    for (int g = 0; g < 3; ++g)
      bfr[g] = *(const short8*)(Bb + (size_t)(wc * 48 + g * 16 + lr) * 64 + cbase);
    __builtin_amdgcn_s_setprio(1);
#pragma unroll
    for (int f = 0; f < 8; ++f)
#pragma unroll
      for (int g = 0; g < 3; ++g)
        acc[f][g] = MFMA16(af[f], bfr[g], acc[f][g]);
    __builtin_amdgcn_s_setprio(0);
    asm volatile("s_waitcnt lgkmcnt(0)" ::: "memory");
    if (ht + 3 < nht)
      asm volatile("s_waitcnt vmcnt(8)" ::: "memory");
    else
      asm volatile("s_waitcnt vmcnt(0)" ::: "memory");
    __builtin_amdgcn_s_barrier();
  }
#undef GSTAGE

  bf16* Qb  = (bf16*)Cp;
  bf16* Kb2 = Qb + (size_t)Bd * NH * Td * HD;
  bf16* Vtb = Kb2 + (size_t)Bd * NKV * Td * HD;

  int b    = m0 >> 11;
  int col0 = n0 + wc * 48;

  if (col0 >= 2560) {
    // ---- whole-V wave: LDS transpose, coalesced stores ----
    int tg = (m0 & 2047) + wr * 128;
    int d0 = col0 - 2560;
    char* tb = lds + w * 14336;                // [48 dl][128 tt] bf16, swizzled
#pragma unroll
    for (int i = 0; i < 8; ++i)
#pragma unroll
      for (int j = 0; j < 3; ++j)
#pragma unroll
        for (int r = 0; r < 4; r += 2) {
          int dl = j * 16 + lr;
          int tt = i * 16 + lg * 4 + r;
          unsigned int pk = pkbf(acc[i][j][r], acc[i][j][r + 1]);
          *(unsigned int*)(tb + (((size_t)dl * 256 + tt * 2) ^ ((dl & 7) << 4))) = pk;
        }
    asm volatile("s_waitcnt lgkmcnt(0)" ::: "memory");
    __builtin_amdgcn_sched_barrier(0);
#pragma unroll
    for (int p = 0; p < 12; ++p) {
      int c  = p * 64 + lane;
      int dl = c >> 4;
      int tc = c & 15;
      int dg = d0 + dl;
      int h  = dg >> 6, dd = dg & 63;
      u32x4 v = *(const u32x4*)(tb + (((size_t)dl * 256 + tc * 16) ^ ((dl & 7) << 4)));
      *(u32x4*)((char*)Vtb + ((((size_t)b * NKV + h) * 64 + dd) * Td + tg) * 2 + tc * 16) = v;
    }
    return;
  }

  // ---- Q/K (+ straddle-V) epilogue with fused RoPE ----
  const float RC  = -0.41524101186092029f;       // -log2(10000)/32
  const float QSC = 0.18033688011112042f;        // 0.125*log2e
  int odd = lane & 1;
#pragma unroll
  for (int j = 0; j < 3; ++j) {
    int ncol = col0 + j * 16 + lr;
    int d  = ncol & 63;
    float inv = __builtin_amdgcn_exp2f((float)(d >> 1) * RC);
#pragma unroll
    for (int i = 0; i < 8; ++i) {
#pragma unroll
      for (int r = 0; r < 4; ++r) {
        int mrow = m0 + wr * 128 + i * 16 + lg * 4 + r;
        int t = mrow & 2047;
        float raw = acc[i][j][r];
        float p = __shfl_xor(raw, 1);
        float rev = (float)t * inv * 0.15915494309189535f;
        rev = rev - floorf(rev);
        float s = __builtin_amdgcn_sinf(rev);
        float c = __builtin_amdgcn_cosf(rev);
        float res = odd ? (raw * c + p * s) : (raw * c - p * s);
        if (ncol < 2048) {
          int h = ncol >> 6;
          Qb[(((size_t)b * NH + h) * Td + t) * HD + d] = __float2bfloat16(res * QSC);
        } else if (ncol < 2560) {
          int h = (ncol - 2048) >> 6;
          Kb2[(((size_t)b * NKV + h) * Td + t) * HD + d] = __float2bfloat16(res);
        } else {
          int dg = ncol - 2560;
          int h = dg >> 6, dd = dg & 63;
          Vtb[(((size_t)b * NKV + h) * 64 + dd) * Td + t] = __float2bfloat16(raw);
        }
      }
    }
  }
}

// ---------------- Out-proj GEMM: 256x128, 8 waves, 4-buf BK=32 pipeline ----
// grid (16,16). Per-wave C = 128x32 (acc 8x2). LDS: A 4x16KB @0 | B 4x8KB
// @65536 = 96 KB. 3 loads/thread/half-tile, vmcnt(6).
__global__ __launch_bounds__(512, 2) void gemm_out(const bf16* __restrict__ A,
                                                   const bf16* __restrict__ Bt,
                                                   float* __restrict__ Cp,
                                                   int M, int N, int K) {
  __shared__ __align__(16) char lds[98304];
  int tid = threadIdx.x;
  int w = tid >> 6, lane = tid & 63;
  int lr = lane & 15, lg = lane >> 4;
  int m0 = blockIdx.x * 256, n0 = blockIdx.y * 128;
  int wr = w >> 2, wc = w & 3;                 // 2M x 4N wave grid
  f32x4 acc[8][2] = {};

  size_t Kb = (size_t)K * 2;
  int srw = lane >> 2;
  int swc = ((lane & 3) ^ (srw & 3)) << 4;
  const char* AsrcT = (const char*)A + (size_t)(m0 + w * 16 + srw) * Kb + swc;
  const char* BsrcT = (const char*)Bt + (size_t)(n0 + w * 16 + srw) * Kb + swc;
  char* AldW = lds + w * 1024;
  char* BldW = lds + 65536 + w * 1024;

#define GSTAGE(ht) do {                                                       \
    int _b = (ht) & 3; size_t _k = (size_t)(ht) * 64;                         \
    GLOAD_LDS16(AsrcT + _k,                      AldW + _b * 16384);          \
    GLOAD_LDS16(AsrcT + (size_t)128 * Kb + _k,   AldW + _b * 16384 + 8192);   \
    GLOAD_LDS16(BsrcT + _k,                      BldW + _b * 8192);           \
  } while (0)

  int nht = K >> 5;
  GSTAGE(0); GSTAGE(1); GSTAGE(2);
  asm volatile("s_waitcnt vmcnt(6)" ::: "memory");
  __builtin_amdgcn_s_barrier();

  int cbase = (lg ^ (lr & 3)) << 4;
  for (int ht = 0; ht < nht; ++ht) {
    int buf = ht & 3;
    if (ht + 3 < nht) GSTAGE(ht + 3);
    const char* Ab = lds + buf * 16384;
    const char* Bb = lds + 65536 + buf * 8192;
    short8 af[8], bfr[2];
#pragma unroll
    for (int f = 0; f < 8; ++f)
      af[f] = *(const short8*)(Ab + (size_t)(wr * 128 + f * 16 + lr) * 64 + cbase);
#pragma unroll
    for (int g = 0; g < 2; ++g)
      bfr[g] = *(const short8*)(Bb + (size_t)(wc * 32 + g * 16 + lr) * 64 + cbase);
    __builtin_amdgcn_s_setprio(1);
#pragma unroll
    for (int f = 0; f < 8; ++f)
#pragma unroll
      for (int g = 0; g < 2; ++g)
        acc[f][g] = MFMA16(af[f], bfr[g], acc[f][g]);
    __builtin_amdgcn_s_setprio(0);
    asm volatile("s_waitcnt lgkmcnt(0)" ::: "memory");
    if (ht + 3 < nht)
      asm volatile("s_waitcnt vmcnt(6)" ::: "memory");
    else
      asm volatile("s_waitcnt vmcnt(0)" ::: "memory");
    __builtin_amdgcn_s_barrier();
  }
#undef GSTAGE

#pragma unroll
  for (int i = 0; i < 8; ++i)
#pragma unroll
    for (int j = 0; j < 2; ++j)
#pragma unroll
      for (int r = 0; r < 4; ++r) {
        int mrow = m0 + wr * 128 + i * 16 + lg * 4 + r;
        int ncol = n0 + wc * 32 + j * 16 + lr;
        Cp[(size_t)mrow * N + ncol] = acc[i][j][r];
      }
}

// ---------------- Flash attention (causal, GQA), LDS-staged KV -------------
__global__ __launch_bounds__(512, 4) void attn_kernel(const bf16* __restrict__ Q,
                                                      const bf16* __restrict__ K,
                                                      const bf16* __restrict__ Vt,
                                                      bf16* __restrict__ Y) {
  __shared__ __align__(16) char lds[2 * 16384];   // [buf][K 8KB | V 8KB]
  int tid = threadIdx.x, w = tid >> 6, lane = tid & 63;
  int lq = lane & 31;
  int H  = lane >> 5;
  int qb = 7 - (int)blockIdx.y;
  int bh = blockIdx.x;
  int b = bh >> 5, h = bh & 31, kvh = h >> 2;
  int q0w = qb * 256 + w * 32;
  int qg  = q0w + lq;
  int tmax = qb * 4 + (w >> 1);
  int Nt   = qb * 4 + 4;

  const bf16* Qp = Q + (((size_t)b * NH + h) * Td) * HD;
  const char* Kg = (const char*)(K + (((size_t)b * NKV + kvh) * Td) * HD);
  const char* Vg = (const char*)(Vt + (((size_t)b * NKV + kvh) * HD) * Td);

  short8 qf[4];
#pragma unroll
  for (int ck = 0; ck < 4; ++ck)
    qf[ck] = *(const short8*)(Qp + (size_t)qg * HD + ck * 16 + H * 8);

  int srow   = lane >> 3;
  int scol16 = ((lane & 7) ^ srow) << 4;
  const char* Ksrc0 = Kg + (size_t)(w * 8 + srow) * 128 + scol16;
  const char* Vsrc0 = Vg + (size_t)(w * 8 + srow) * 4096 + scol16;
  char* KldsW[2] = { lds + w * 1024,          lds + 16384 + w * 1024 };
  char* VldsW[2] = { lds + 8192 + w * 1024,   lds + 24576 + w * 1024 };

#define STAGE_KV(tt, bb) do {                                                 \
    GLOAD_LDS16(Ksrc0 + (size_t)(tt) * 64 * 128, KldsW[bb]);                  \
    GLOAD_LDS16(Vsrc0 + (size_t)(tt) * 128,      VldsW[bb]);                  \
  } while (0)

  f32x16 acc0 = {}, acc1 = {};
  float m = -3e38f, l = 0.0f;
  int swz = (lq & 7) << 4;
  int rb0 = lq * 128, rb1 = (32 + lq) * 128;

  STAGE_KV(0, 0);
  asm volatile("s_waitcnt vmcnt(0)" ::: "memory");
  __syncthreads();

  for (int t = 0; t < Nt; ++t) {
    int cur = t & 1;
    if (t + 1 < Nt) STAGE_KV(t + 1, cur ^ 1);
    if (t <= tmax) {
      const char* Kl = lds + cur * 16384;
      const char* Vl = Kl + 8192;
      f32x16 s0 = {}, s1 = {};
      __builtin_amdgcn_s_setprio(1);
#pragma unroll
      for (int ck = 0; ck < 4; ++ck) {
        int c = (H * 16 + ck * 32) ^ swz;
        short8 kf0 = *(const short8*)(Kl + rb0 + c);
        short8 kf1 = *(const short8*)(Kl + rb1 + c);
        s0 = MFMA32(kf0, qf[ck], s0);
        s1 = MFMA32(kf1, qf[ck], s1);
      }
      __builtin_amdgcn_s_setprio(0);
      if (t == tmax) {
        int kvb = t * 64;
#pragma unroll
        for (int rr = 0; rr < 16; ++rr) {
          int krel = (rr & 3) + 8 * (rr >> 2) + 4 * H;
          if (kvb + krel > qg)      s0[rr] = -3e38f;
          if (kvb + 32 + krel > qg) s1[rr] = -3e38f;
        }
      }
      float mx = fmaxf(hmax16(s0), hmax16(s1));
      {
        float mb = mx;
        asm("" : "+v"(mb));
        plswapf(mx, mb);
        mx = fmaxf(mx, mb);
      }
      if (__any(mx > m + 8.0f)) {
        float mn = fmaxf(m, mx);
        float al = __builtin_amdgcn_exp2f(m - mn);
        m = mn;
        l *= al;
#pragma unroll
        for (int rr = 0; rr < 16; ++rr) { acc0[rr] *= al; acc1[rr] *= al; }
      }
#pragma unroll
      for (int rr = 0; rr < 16; ++rr) {
        s0[rr] = __builtin_amdgcn_exp2f(s0[rr] - m);
        s1[rr] = __builtin_amdgcn_exp2f(s1[rr] - m);
      }
      float ps = hsum16(s0) + hsum16(s1);
      {
        float pb = ps;
        asm("" : "+v"(pb));
        plswapf(ps, pb);
        ps += pb;
      }
      l += ps;
      short8 pf[4];
#pragma unroll
      for (int tt = 0; tt < 2; ++tt) {
        const f32x16& sv = tt ? s1 : s0;
#pragma unroll
        for (int a2 = 0; a2 < 2; ++a2) {
          unsigned int A0 = pkbf(sv[8*a2 + 0], sv[8*a2 + 1]);
          unsigned int A1 = pkbf(sv[8*a2 + 2], sv[8*a2 + 3]);
          unsigned int B0 = pkbf(sv[8*a2 + 4], sv[8*a2 + 5]);
          unsigned int B1 = pkbf(sv[8*a2 + 6], sv[8*a2 + 7]);
          plswapu(A0, B0);
          plswapu(A1, B1);
          u32x4 t4;
          t4[0] = A0; t4[1] = A1; t4[2] = B0; t4[3] = B1;
          pf[2*tt + a2] = __builtin_bit_cast(short8, t4);
        }
      }
      __builtin_amdgcn_s_setprio(1);
#pragma unroll
      for (int ks = 0; ks < 4; ++ks) {
        int c = (H * 16 + ks * 32) ^ swz;
        short8 vf0 = *(const short8*)(Vl + rb0 + c);
        short8 vf1 = *(const short8*)(Vl + rb1 + c);
        acc0 = MFMA32(vf0, pf[ks], acc0);
        acc1 = MFMA32(vf1, pf[ks], acc1);
      }
      __builtin_amdgcn_s_setprio(0);
    }
    asm volatile("s_waitcnt vmcnt(0)" ::: "memory");
    __syncthreads();
  }
#undef STAGE_KV

  float rn = 1.0f / l;
  bf16* Yp = Y + ((size_t)b * Td + qg) * Cd + h * HD;
#pragma unroll
  for (int rr = 0; rr < 16; rr += 2) {
    int d = (rr & 3) + 8 * (rr >> 2) + 4 * H;
    unsigned int w0 = pkbf(acc0[rr] * rn, acc0[rr + 1] * rn);
    unsigned int w1 = pkbf(acc1[rr] * rn, acc1[rr + 1] * rn);
    *(unsigned int*)(Yp + d)      = w0;
    *(unsigned int*)(Yp + 32 + d) = w1;
  }
}

// ---------------------------------------------------------------------------
extern "C" void kernel_launch(void* const* d_in, const int* in_sizes, int n_in,
                              void* d_out, int out_size, void* d_ws, size_t ws_size,
                              hipStream_t stream) {
  const float* x  = (const float*)d_in[0];
  const float* wq = (const float*)d_in[1];
  const float* wk = (const float*)d_in[2];
  const float* wv = (const float*)d_in[3];
  const float* wo = (const float*)d_in[4];

  char* ws = (char*)d_ws;
  const size_t o_xb  = 0;                                    // 16.78 MB (reused as yb)
  const size_t o_w1  = o_xb + (size_t)Md * Cd * 2;           // 12.58 MB (wqkvT)
  const size_t o_Q   = o_w1 + (size_t)3072 * Cd * 2;         // 16.78 MB
  const size_t o_K   = o_Q + (size_t)Bd * NH * Td * HD * 2;  // 4.19 MB
  const size_t o_V   = o_K + (size_t)Bd * NKV * Td * HD * 2; // 4.19 MB
  const size_t o_woT = o_V + (size_t)Bd * NKV * HD * Td * 2; // 8.39 MB (fused path)
  const size_t need  = o_woT + (size_t)Cd * Cd * 2;

  bf16* xb  = (bf16*)(ws + o_xb);
  bf16* w1  = (bf16*)(ws + o_w1);
  bf16* Qb  = (bf16*)(ws + o_Q);
  bf16* Kb  = (bf16*)(ws + o_K);
  bf16* Vtb = (bf16*)(ws + o_V);
  bf16* yb  = xb;   // alias: x_bf16 dead after QKV GEMM

  bool fused = (ws_size >= need);
  bf16* woT = fused ? (bf16*)(ws + o_woT) : w1;

  // 1. prep1: x->bf16 + wq/wk/wv (+wo if ws allows) transposes
  prep1_kernel<<<dim3(fused ? 18432 : 14336), dim3(256), 0, stream>>>(
      x, wq, wk, wv, wo, xb, w1, woT);
  // 2. fused QKV projection (N = 3072) with in-epilogue RoPE; 256x192 tiles
  gemm_qkv<<<dim3(Md / 256, 3072 / 192), dim3(512), 0, stream>>>(xb, w1, Qb, Md, 3072, Cd);
  // 3. (fallback only) wo transpose into w1
  if (!fused)
    transpose_f2b<<<dim3(Cd / 32, Cd / 32), dim3(256), 0, stream>>>(wo, w1, Cd, Cd);
  // 4. attention -> yb (bf16 [M][C]); 8-wave LDS-staged blocks, LPT order
  attn_kernel<<<dim3(Bd * NH, 8), dim3(512), 0, stream>>>(Qb, Kb, Vtb, yb);
  // 5. output projection -> d_out (fp32); 256x128 tiles, full-chip grid
  gemm_out<<<dim3(Md / 256, Cd / 128), dim3(512), 0, stream>>>(yb, woT, (float*)d_out, Md, Cd, Cd);
}

// Round 17
// 176.235 us; speedup vs baseline: 1.0951x; 1.0951x over previous
//
#include <hip/hip_runtime.h>
#include <hip/hip_bf16.h>
#include <cstdint>
#include <cstddef>

// ---------------------------------------------------------------------------
// LlamaAttention forward: out = Attn(RoPE(x@wq), RoPE(x@wk), x@wv) @ wo
// B=2 T=2048 C=2048 NH=32 NKV=8 D=64, causal, GQA rep=4, scale=1/8.
// R17: revert R16 (BK=32 4-buf regressed: 4-chunk swizzle -> 5.8M conflicts,
// half the MFMA per read batch). Base = R15 (183us). GEMM K-loops
// restructured: issue ALL 22 ds_reads once (A-lo, B, A-hi; order pinned),
// lgkmcnt(8) -> MFMA-lo overlaps in-flight A-hi reads, lgkmcnt(0) ->
// MFMA-hi, ONE barrier/tile (was 4). LDS-read pipe is the binding resource
// (2112cy/tile vs 466 MFMA); this removes its serialization.
// ---------------------------------------------------------------------------

using bf16 = __hip_bfloat16;
using f32x4  = __attribute__((ext_vector_type(4))) float;
using f32x16 = __attribute__((ext_vector_type(16))) float;
using short8 = __attribute__((ext_vector_type(8))) short;
using u32x4  = __attribute__((ext_vector_type(4))) unsigned int;

typedef __attribute__((address_space(1))) const void* gp1_t;
typedef __attribute__((address_space(3))) void*       lp3_t;

#define GLOAD_LDS16(g, l)                                                     \
  __builtin_amdgcn_global_load_lds((gp1_t)(const void*)(g), (lp3_t)(void*)(l), 16, 0, 0)

#define MFMA16(a, b, c) __builtin_amdgcn_mfma_f32_16x16x32_bf16(a, b, c, 0, 0, 0)
#define MFMA32(a, b, c) __builtin_amdgcn_mfma_f32_32x32x16_bf16(a, b, c, 0, 0, 0)

static constexpr int Bd  = 2;
static constexpr int Td  = 2048;
static constexpr int Cd  = 2048;
static constexpr int NH  = 32;
static constexpr int NKV = 8;
static constexpr int HD  = 64;
static constexpr int Md  = Bd * Td;     // 4096 rows

__device__ inline float bf2f(unsigned short u) {
  union { unsigned int i; float f; } v; v.i = ((unsigned int)u) << 16; return v.f;
}
__device__ inline unsigned short f2bfbits(float f) {
  union { float f; unsigned int u; } v; v.f = f;
  unsigned int r = v.u + 0x7fffu + ((v.u >> 16) & 1u);   // RNE
  return (unsigned short)(r >> 16);
}
__device__ inline unsigned int pkbf(float a, float b) {   // lo=bf16(a), hi=bf16(b)
  unsigned int r;
  asm("v_cvt_pk_bf16_f32 %0, %1, %2" : "=v"(r) : "v"(a), "v"(b));
  return r;
}
// v_permlane32_swap_b32 d, s:  after: d = {d.lo, s.lo}, s = {d.hi, s.hi}.
__device__ inline void plswapf(float& a, float& b) {
  asm("v_permlane32_swap_b32 %0, %1" : "+v"(a), "+v"(b));
}
__device__ inline void plswapu(unsigned int& a, unsigned int& b) {
  asm("v_permlane32_swap_b32 %0, %1" : "+v"(a), "+v"(b));
}
__device__ inline float hmax16(const f32x16& v) {
  float a0 = fmaxf(v[0], v[1]),   a1 = fmaxf(v[2], v[3]);
  float a2 = fmaxf(v[4], v[5]),   a3 = fmaxf(v[6], v[7]);
  float a4 = fmaxf(v[8], v[9]),   a5 = fmaxf(v[10], v[11]);
  float a6 = fmaxf(v[12], v[13]), a7 = fmaxf(v[14], v[15]);
  float b0 = fmaxf(a0, a1), b1 = fmaxf(a2, a3);
  float b2 = fmaxf(a4, a5), b3 = fmaxf(a6, a7);
  return fmaxf(fmaxf(b0, b1), fmaxf(b2, b3));
}
__device__ inline float hsum16(const f32x16& v) {
  float a0 = v[0]+v[1],   a1 = v[2]+v[3],   a2 = v[4]+v[5],   a3 = v[6]+v[7];
  float a4 = v[8]+v[9],   a5 = v[10]+v[11], a6 = v[12]+v[13], a7 = v[14]+v[15];
  float b0 = a0+a1, b1 = a2+a3, b2 = a4+a5, b3 = a6+a7;
  return (b0+b1)+(b2+b3);
}

// ---------------- prep1: x->bf16 + wq/wk/wv (+wo) fp32->bf16^T -------------
__global__ __launch_bounds__(256) void prep1_kernel(const float* __restrict__ x,
                                                    const float* __restrict__ wq,
                                                    const float* __restrict__ wk,
                                                    const float* __restrict__ wv,
                                                    const float* __restrict__ wo,
                                                    bf16* __restrict__ xb,
                                                    bf16* __restrict__ w1,
                                                    bf16* __restrict__ woT) {
  __shared__ float tile[32][33];
  int bid = blockIdx.x, tid = threadIdx.x;
  if (bid < 8192) {
    int i = bid * 256 + tid;
    float4 v = ((const float4*)x)[i];
    ushort4 o;
    o.x = f2bfbits(v.x); o.y = f2bfbits(v.y); o.z = f2bfbits(v.z); o.w = f2bfbits(v.w);
    ((ushort4*)xb)[i] = o;
    return;
  }
  const float* in; bf16* out; int Cc, bx, by;
  if (bid < 12288)      { int l = bid - 8192;  in = wq; out = w1;                        Cc = 2048; bx = l & 63; by = l >> 6; }
  else if (bid < 13312) { int l = bid - 12288; in = wk; out = w1 + (size_t)2048 * 2048;  Cc = 512;  bx = l & 15; by = l >> 4; }
  else if (bid < 14336) { int l = bid - 13312; in = wv; out = w1 + (size_t)2560 * 2048;  Cc = 512;  bx = l & 15; by = l >> 4; }
  else                  { int l = bid - 14336; in = wo; out = woT;                       Cc = 2048; bx = l & 63; by = l >> 6; }
  int tx = tid & 31, ty = tid >> 5;
  int col = bx * 32 + tx;
#pragma unroll
  for (int i = 0; i < 4; ++i) {
    int row = by * 32 + ty + i * 8;
    tile[ty + i * 8][tx] = in[(size_t)row * Cc + col];
  }
  __syncthreads();
#pragma unroll
  for (int i = 0; i < 4; ++i) {
    int orow = bx * 32 + ty + i * 8;
    int ocol = by * 32 + tx;
    out[(size_t)orow * 2048 + ocol] = __float2bfloat16(tile[tx][ty + i * 8]);
  }
}

// ---------------- fp32 [R][Cc] -> bf16 transpose [Cc][R] (fallback wo) -----
__global__ __launch_bounds__(256) void transpose_f2b(const float* __restrict__ in,
                                                     bf16* __restrict__ out,
                                                     int R, int Cc) {
  __shared__ float tile[32][33];
  int tx = threadIdx.x & 31, ty = threadIdx.x >> 5;
  int bx = blockIdx.x, by = blockIdx.y;
  int col = bx * 32 + tx;
#pragma unroll
  for (int i = 0; i < 4; ++i) {
    int row = by * 32 + ty + i * 8;
    tile[ty + i * 8][tx] = in[(size_t)row * Cc + col];
  }
  __syncthreads();
#pragma unroll
  for (int i = 0; i < 4; ++i) {
    int orow = bx * 32 + ty + i * 8;
    int ocol = by * 32 + tx;
    out[(size_t)orow * R + ocol] = __float2bfloat16(tile[tx][ty + i * 8]);
  }
}

// ---------------- QKV GEMM: 256x192 tile, 8 waves, fused-read loop ---------
// grid (16,16) = 256 blocks (full chip). Per-wave C = 128x48 (acc 8x3).
// LDS: A dbuf 2x32KB @0 | B dbuf 2x24KB @65536 = 112 KB. (row&7) XOR swizzle.
// Per K-tile: stage(t+1); issue 22 ds_reads (A-lo,B | A-hi); lgkm(8);
// 24 MFMA-lo (A-hi in flight); lgkm(0); 24 MFMA-hi; vmcnt(0); barrier.
__global__ __launch_bounds__(512, 2) void gemm_qkv(const bf16* __restrict__ A,
                                                   const bf16* __restrict__ Bt,
                                                   void* __restrict__ Cp,
                                                   int M, int N, int K) {
  __shared__ __align__(16) char lds[114688];
  int tid = threadIdx.x;
  int w = tid >> 6, lane = tid & 63;
  int lr = lane & 15, lg = lane >> 4;
  int m0 = blockIdx.x * 256, n0 = blockIdx.y * 192;
  int wr = w >> 2, wc = w & 3;                 // 2M x 4N wave grid
  f32x4 acc[8][3] = {};

  size_t Kb = (size_t)K * 2;
  int c8 = lane & 7, r8 = lane >> 3;
  const char* Asrc = (const char*)A + (size_t)(m0 + w * 8 + r8) * Kb + ((c8 ^ r8) << 4);
  const char* Bsrc = (const char*)Bt + (size_t)(n0 + w * 8 + r8) * Kb + ((c8 ^ r8) << 4);
  char* AldsW = lds + w * 1024;
  char* BldsW = lds + 65536 + w * 1024;

#define GSTAGE(kt, bb) do {                                                   \
    _Pragma("unroll")                                                         \
    for (int j = 0; j < 4; ++j)                                               \
      GLOAD_LDS16(Asrc + (size_t)j * 64 * Kb + (size_t)(kt) * 2,              \
                  AldsW + (bb) * 32768 + j * 8192);                           \
    _Pragma("unroll")                                                         \
    for (int j = 0; j < 3; ++j)                                               \
      GLOAD_LDS16(Bsrc + (size_t)j * 64 * Kb + (size_t)(kt) * 2,              \
                  BldsW + (bb) * 24576 + j * 8192);                           \
  } while (0)

  int nkt = K >> 6;
  GSTAGE(0, 0);
  asm volatile("s_waitcnt vmcnt(0)" ::: "memory");
  __builtin_amdgcn_s_barrier();

  for (int t = 0; t < nkt; ++t) {
    int cur = t & 1;
    const char* Ab = lds + cur * 32768;
    const char* Bb = lds + 65536 + cur * 24576;
    short8 af[4][2], ah[4][2], bfr[3][2];

    if (t + 1 < nkt) GSTAGE((t + 1) << 6, cur ^ 1);
    // ---- issue group 1: A-lo (8) + B (6) ----
#pragma unroll
    for (int kk = 0; kk < 2; ++kk) {
      int cb = (((kk << 2) | lg) ^ (lr & 7)) << 4;
#pragma unroll
      for (int f = 0; f < 4; ++f)
        af[f][kk] = *(const short8*)(Ab + (size_t)(wr * 128 + f * 16 + lr) * 128 + cb);
#pragma unroll
      for (int g = 0; g < 3; ++g)
        bfr[g][kk] = *(const short8*)(Bb + (size_t)(wc * 48 + g * 16 + lr) * 128 + cb);
    }
    __builtin_amdgcn_sched_barrier(0);
    // ---- issue group 2: A-hi (8) ----
#pragma unroll
    for (int kk = 0; kk < 2; ++kk) {
      int cb = (((kk << 2) | lg) ^ (lr & 7)) << 4;
#pragma unroll
      for (int f = 0; f < 4; ++f)
        ah[f][kk] = *(const short8*)(Ab + (size_t)(wr * 128 + 64 + f * 16 + lr) * 128 + cb);
    }
    __builtin_amdgcn_sched_barrier(0);
    asm volatile("s_waitcnt lgkmcnt(8)" ::: "memory");   // group 1 landed
    __builtin_amdgcn_sched_barrier(0);
    __builtin_amdgcn_s_setprio(1);
#pragma unroll
    for (int f = 0; f < 4; ++f)
#pragma unroll
      for (int g = 0; g < 3; ++g)
#pragma unroll
        for (int kk = 0; kk < 2; ++kk)
          acc[f][g] = MFMA16(af[f][kk], bfr[g][kk], acc[f][g]);
    __builtin_amdgcn_s_setprio(0);
    asm volatile("s_waitcnt lgkmcnt(0)" ::: "memory");   // A-hi landed
    __builtin_amdgcn_sched_barrier(0);
    __builtin_amdgcn_s_setprio(1);
#pragma unroll
    for (int f = 0; f < 4; ++f)
#pragma unroll
      for (int g = 0; g < 3; ++g)
#pragma unroll
        for (int kk = 0; kk < 2; ++kk)
          acc[4 + f][g] = MFMA16(ah[f][kk], bfr[g][kk], acc[4 + f][g]);
    __builtin_amdgcn_s_setprio(0);
    __builtin_amdgcn_sched_barrier(0);
    asm volatile("s_waitcnt vmcnt(0)" ::: "memory");     // stage(t+1) landed
    __builtin_amdgcn_s_barrier();                        // one barrier/tile
  }
#undef GSTAGE

  bf16* Qb  = (bf16*)Cp;
  bf16* Kb2 = Qb + (size_t)Bd * NH * Td * HD;
  bf16* Vtb = Kb2 + (size_t)Bd * NKV * Td * HD;

  int b    = m0 >> 11;
  int col0 = n0 + wc * 48;

  if (col0 >= 2560) {
    // ---- whole-V wave: LDS transpose, coalesced stores ----
    int tg = (m0 & 2047) + wr * 128;
    int d0 = col0 - 2560;
    char* tb = lds + w * 14336;                // [48 dl][128 tt] bf16, swizzled
#pragma unroll
    for (int i = 0; i < 8; ++i)
#pragma unroll
      for (int j = 0; j < 3; ++j)
#pragma unroll
        for (int r = 0; r < 4; r += 2) {
          int dl = j * 16 + lr;
          int tt = i * 16 + lg * 4 + r;
          unsigned int pk = pkbf(acc[i][j][r], acc[i][j][r + 1]);
          *(unsigned int*)(tb + (((size_t)dl * 256 + tt * 2) ^ ((dl & 7) << 4))) = pk;
        }
    asm volatile("s_waitcnt lgkmcnt(0)" ::: "memory");
    __builtin_amdgcn_sched_barrier(0);
#pragma unroll
    for (int p = 0; p < 12; ++p) {
      int c  = p * 64 + lane;
      int dl = c >> 4;
      int tc = c & 15;
      int dg = d0 + dl;
      int h  = dg >> 6, dd = dg & 63;
      u32x4 v = *(const u32x4*)(tb + (((size_t)dl * 256 + tc * 16) ^ ((dl & 7) << 4)));
      *(u32x4*)((char*)Vtb + ((((size_t)b * NKV + h) * 64 + dd) * Td + tg) * 2 + tc * 16) = v;
    }
    return;
  }

  // ---- Q/K (+ straddle-V) epilogue with fused RoPE ----
  const float RC  = -0.41524101186092029f;       // -log2(10000)/32
  const float QSC = 0.18033688011112042f;        // 0.125*log2e
  int odd = lane & 1;
#pragma unroll
  for (int j = 0; j < 3; ++j) {
    int ncol = col0 + j * 16 + lr;
    int d  = ncol & 63;
    float inv = __builtin_amdgcn_exp2f((float)(d >> 1) * RC);
#pragma unroll
    for (int i = 0; i < 8; ++i) {
#pragma unroll
      for (int r = 0; r < 4; ++r) {
        int mrow = m0 + wr * 128 + i * 16 + lg * 4 + r;
        int t = mrow & 2047;
        float raw = acc[i][j][r];
        float p = __shfl_xor(raw, 1);
        float rev = (float)t * inv * 0.15915494309189535f;
        rev = rev - floorf(rev);
        float s = __builtin_amdgcn_sinf(rev);
        float c = __builtin_amdgcn_cosf(rev);
        float res = odd ? (raw * c + p * s) : (raw * c - p * s);
        if (ncol < 2048) {
          int h = ncol >> 6;
          Qb[(((size_t)b * NH + h) * Td + t) * HD + d] = __float2bfloat16(res * QSC);
        } else if (ncol < 2560) {
          int h = (ncol - 2048) >> 6;
          Kb2[(((size_t)b * NKV + h) * Td + t) * HD + d] = __float2bfloat16(res);
        } else {
          int dg = ncol - 2560;
          int h = dg >> 6, dd = dg & 63;
          Vtb[(((size_t)b * NKV + h) * 64 + dd) * Td + t] = __float2bfloat16(raw);
        }
      }
    }
  }
}

// ---------------- Out-proj GEMM: 256x128, 8 waves, fused-read loop ---------
// grid (16,16). Per-wave C = 128x32 (acc 8x2). LDS: A 2x32KB | B 2x16KB.
// Per K-tile: stage; 20 ds_reads (A-lo,B | A-hi); lgkm(8); 16 MFMA-lo;
// lgkm(0); 16 MFMA-hi; vmcnt(0); barrier.
__global__ __launch_bounds__(512, 2) void gemm_out(const bf16* __restrict__ A,
                                                   const bf16* __restrict__ Bt,
                                                   float* __restrict__ Cp,
                                                   int M, int N, int K) {
  __shared__ __align__(16) char lds[98304];
  int tid = threadIdx.x;
  int w = tid >> 6, lane = tid & 63;
  int lr = lane & 15, lg = lane >> 4;
  int m0 = blockIdx.x * 256, n0 = blockIdx.y * 128;
  int wr = w >> 2, wc = w & 3;                 // 2M x 4N wave grid
  f32x4 acc[8][2] = {};

  size_t Kb = (size_t)K * 2;
  int c8 = lane & 7, r8 = lane >> 3;
  const char* Asrc = (const char*)A + (size_t)(m0 + w * 8 + r8) * Kb + ((c8 ^ r8) << 4);
  const char* Bsrc = (const char*)Bt + (size_t)(n0 + w * 8 + r8) * Kb + ((c8 ^ r8) << 4);
  char* AldsW = lds + w * 1024;
  char* BldsW = lds + 65536 + w * 1024;

#define GSTAGE(kt, bb) do {                                                   \
    _Pragma("unroll")                                                         \
    for (int j = 0; j < 4; ++j)                                               \
      GLOAD_LDS16(Asrc + (size_t)j * 64 * Kb + (size_t)(kt) * 2,              \
                  AldsW + (bb) * 32768 + j * 8192);                           \
    _Pragma("unroll")                                                         \
    for (int j = 0; j < 2; ++j)                                               \
      GLOAD_LDS16(Bsrc + (size_t)j * 64 * Kb + (size_t)(kt) * 2,              \
                  BldsW + (bb) * 16384 + j * 8192);                           \
  } while (0)

  int nkt = K >> 6;
  GSTAGE(0, 0);
  asm volatile("s_waitcnt vmcnt(0)" ::: "memory");
  __builtin_amdgcn_s_barrier();

  for (int t = 0; t < nkt; ++t) {
    int cur = t & 1;
    const char* Ab = lds + cur * 32768;
    const char* Bb = lds + 65536 + cur * 16384;
    short8 af[4][2], ah[4][2], bfr[2][2];

    if (t + 1 < nkt) GSTAGE((t + 1) << 6, cur ^ 1);
    // ---- issue group 1: A-lo (8) + B (4) ----
#pragma unroll
    for (int kk = 0; kk < 2; ++kk) {
      int cb = (((kk << 2) | lg) ^ (lr & 7)) << 4;
#pragma unroll
      for (int f = 0; f < 4; ++f)
        af[f][kk] = *(const short8*)(Ab + (size_t)(wr * 128 + f * 16 + lr) * 128 + cb);
#pragma unroll
      for (int g = 0; g < 2; ++g)
        bfr[g][kk] = *(const short8*)(Bb + (size_t)(wc * 32 + g * 16 + lr) * 128 + cb);
    }
    __builtin_amdgcn_sched_barrier(0);
    // ---- issue group 2: A-hi (8) ----
#pragma unroll
    for (int kk = 0; kk < 2; ++kk) {
      int cb = (((kk << 2) | lg) ^ (lr & 7)) << 4;
#pragma unroll
      for (int f = 0; f < 4; ++f)
        ah[f][kk] = *(const short8*)(Ab + (size_t)(wr * 128 + 64 + f * 16 + lr) * 128 + cb);
    }
    __builtin_amdgcn_sched_barrier(0);
    asm volatile("s_waitcnt lgkmcnt(8)" ::: "memory");   // group 1 landed
    __builtin_amdgcn_sched_barrier(0);
    __builtin_amdgcn_s_setprio(1);
#pragma unroll
    for (int f = 0; f < 4; ++f)
#pragma unroll
      for (int g = 0; g < 2; ++g)
#pragma unroll
        for (int kk = 0; kk < 2; ++kk)
          acc[f][g] = MFMA16(af[f][kk], bfr[g][kk], acc[f][g]);
    __builtin_amdgcn_s_setprio(0);
    asm volatile("s_waitcnt lgkmcnt(0)" ::: "memory");   // A-hi landed
    __builtin_amdgcn_sched_barrier(0);
    __builtin_amdgcn_s_setprio(1);
#pragma unroll
    for (int f = 0; f < 4; ++f)
#pragma unroll
      for (int g = 0; g < 2; ++g)
#pragma unroll
        for (int kk = 0; kk < 2; ++kk)
          acc[4 + f][g] = MFMA16(ah[f][kk], bfr[g][kk], acc[4 + f][g]);
    __builtin_amdgcn_s_setprio(0);
    __builtin_amdgcn_sched_barrier(0);
    asm volatile("s_waitcnt vmcnt(0)" ::: "memory");
    __builtin_amdgcn_s_barrier();
  }
#undef GSTAGE

#pragma unroll
  for (int i = 0; i < 8; ++i)
#pragma unroll
    for (int j = 0; j < 2; ++j)
#pragma unroll
      for (int r = 0; r < 4; ++r) {
        int mrow = m0 + wr * 128 + i * 16 + lg * 4 + r;
        int ncol = n0 + wc * 32 + j * 16 + lr;
        Cp[(size_t)mrow * N + ncol] = acc[i][j][r];
      }
}

// ---------------- Flash attention (causal, GQA), LDS-staged KV -------------
__global__ __launch_bounds__(512, 4) void attn_kernel(const bf16* __restrict__ Q,
                                                      const bf16* __restrict__ K,
                                                      const bf16* __restrict__ Vt,
                                                      bf16* __restrict__ Y) {
  __shared__ __align__(16) char lds[2 * 16384];   // [buf][K 8KB | V 8KB]
  int tid = threadIdx.x, w = tid >> 6, lane = tid & 63;
  int lq = lane & 31;
  int H  = lane >> 5;
  int qb = 7 - (int)blockIdx.y;
  int bh = blockIdx.x;
  int b = bh >> 5, h = bh & 31, kvh = h >> 2;
  int q0w = qb * 256 + w * 32;
  int qg  = q0w + lq;
  int tmax = qb * 4 + (w >> 1);
  int Nt   = qb * 4 + 4;

  const bf16* Qp = Q + (((size_t)b * NH + h) * Td) * HD;
  const char* Kg = (const char*)(K + (((size_t)b * NKV + kvh) * Td) * HD);
  const char* Vg = (const char*)(Vt + (((size_t)b * NKV + kvh) * HD) * Td);

  short8 qf[4];
#pragma unroll
  for (int ck = 0; ck < 4; ++ck)
    qf[ck] = *(const short8*)(Qp + (size_t)qg * HD + ck * 16 + H * 8);

  int srow   = lane >> 3;
  int scol16 = ((lane & 7) ^ srow) << 4;
  const char* Ksrc0 = Kg + (size_t)(w * 8 + srow) * 128 + scol16;
  const char* Vsrc0 = Vg + (size_t)(w * 8 + srow) * 4096 + scol16;
  char* KldsW[2] = { lds + w * 1024,          lds + 16384 + w * 1024 };
  char* VldsW[2] = { lds + 8192 + w * 1024,   lds + 24576 + w * 1024 };

#define STAGE_KV(tt, bb) do {                                                 \
    GLOAD_LDS16(Ksrc0 + (size_t)(tt) * 64 * 128, KldsW[bb]);                  \
    GLOAD_LDS16(Vsrc0 + (size_t)(tt) * 128,      VldsW[bb]);                  \
  } while (0)

  f32x16 acc0 = {}, acc1 = {};
  float m = -3e38f, l = 0.0f;
  int swz = (lq & 7) << 4;
  int rb0 = lq * 128, rb1 = (32 + lq) * 128;

  STAGE_KV(0, 0);
  asm volatile("s_waitcnt vmcnt(0)" ::: "memory");
  __syncthreads();

  for (int t = 0; t < Nt; ++t) {
    int cur = t & 1;
    if (t + 1 < Nt) STAGE_KV(t + 1, cur ^ 1);
    if (t <= tmax) {
      const char* Kl = lds + cur * 16384;
      const char* Vl = Kl + 8192;
      f32x16 s0 = {}, s1 = {};
      __builtin_amdgcn_s_setprio(1);
#pragma unroll
      for (int ck = 0; ck < 4; ++ck) {
        int c = (H * 16 + ck * 32) ^ swz;
        short8 kf0 = *(const short8*)(Kl + rb0 + c);
        short8 kf1 = *(const short8*)(Kl + rb1 + c);
        s0 = MFMA32(kf0, qf[ck], s0);
        s1 = MFMA32(kf1, qf[ck], s1);
      }
      __builtin_amdgcn_s_setprio(0);
      if (t == tmax) {
        int kvb = t * 64;
#pragma unroll
        for (int rr = 0; rr < 16; ++rr) {
          int krel = (rr & 3) + 8 * (rr >> 2) + 4 * H;
          if (kvb + krel > qg)      s0[rr] = -3e38f;
          if (kvb + 32 + krel > qg) s1[rr] = -3e38f;
        }
      }
      float mx = fmaxf(hmax16(s0), hmax16(s1));
      {
        float mb = mx;
        asm("" : "+v"(mb));
        plswapf(mx, mb);
        mx = fmaxf(mx, mb);
      }
      if (__any(mx > m + 8.0f)) {
        float mn = fmaxf(m, mx);
        float al = __builtin_amdgcn_exp2f(m - mn);
        m = mn;
        l *= al;
#pragma unroll
        for (int rr = 0; rr < 16; ++rr) { acc0[rr] *= al; acc1[rr] *= al; }
      }
#pragma unroll
      for (int rr = 0; rr < 16; ++rr) {
        s0[rr] = __builtin_amdgcn_exp2f(s0[rr] - m);
        s1[rr] = __builtin_amdgcn_exp2f(s1[rr] - m);
      }
      float ps = hsum16(s0) + hsum16(s1);
      {
        float pb = ps;
        asm("" : "+v"(pb));
        plswapf(ps, pb);
        ps += pb;
      }
      l += ps;
      short8 pf[4];
#pragma unroll
      for (int tt = 0; tt < 2; ++tt) {
        const f32x16& sv = tt ? s1 : s0;
#pragma unroll
        for (int a2 = 0; a2 < 2; ++a2) {
          unsigned int A0 = pkbf(sv[8*a2 + 0], sv[8*a2 + 1]);
          unsigned int A1 = pkbf(sv[8*a2 + 2], sv[8*a2 + 3]);
          unsigned int B0 = pkbf(sv[8*a2 + 4], sv[8*a2 + 5]);
          unsigned int B1 = pkbf(sv[8*a2 + 6], sv[8*a2 + 7]);
          plswapu(A0, B0);
          plswapu(A1, B1);
          u32x4 t4;
          t4[0] = A0; t4[1] = A1; t4[2] = B0; t4[3] = B1;
          pf[2*tt + a2] = __builtin_bit_cast(short8, t4);
        }
      }
      __builtin_amdgcn_s_setprio(1);
#pragma unroll
      for (int ks = 0; ks < 4; ++ks) {
        int c = (H * 16 + ks * 32) ^ swz;
        short8 vf0 = *(const short8*)(Vl + rb0 + c);
        short8 vf1 = *(const short8*)(Vl + rb1 + c);
        acc0 = MFMA32(vf0, pf[ks], acc0);
        acc1 = MFMA32(vf1, pf[ks], acc1);
      }
      __builtin_amdgcn_s_setprio(0);
    }
    asm volatile("s_waitcnt vmcnt(0)" ::: "memory");
    __syncthreads();
  }
#undef STAGE_KV

  float rn = 1.0f / l;
  bf16* Yp = Y + ((size_t)b * Td + qg) * Cd + h * HD;
#pragma unroll
  for (int rr = 0; rr < 16; rr += 2) {
    int d = (rr & 3) + 8 * (rr >> 2) + 4 * H;
    unsigned int w0 = pkbf(acc0[rr] * rn, acc0[rr + 1] * rn);
    unsigned int w1 = pkbf(acc1[rr] * rn, acc1[rr + 1] * rn);
    *(unsigned int*)(Yp + d)      = w0;
    *(unsigned int*)(Yp + 32 + d) = w1;
  }
}

// ---------------------------------------------------------------------------
extern "C" void kernel_launch(void* const* d_in, const int* in_sizes, int n_in,
                              void* d_out, int out_size, void* d_ws, size_t ws_size,
                              hipStream_t stream) {
  const float* x  = (const float*)d_in[0];
  const float* wq = (const float*)d_in[1];
  const float* wk = (const float*)d_in[2];
  const float* wv = (const float*)d_in[3];
  const float* wo = (const float*)d_in[4];

  char* ws = (char*)d_ws;
  const size_t o_xb  = 0;                                    // 16.78 MB (reused as yb)
  const size_t o_w1  = o_xb + (size_t)Md * Cd * 2;           // 12.58 MB (wqkvT)
  const size_t o_Q   = o_w1 + (size_t)3072 * Cd * 2;         // 16.78 MB
  const size_t o_K   = o_Q + (size_t)Bd * NH * Td * HD * 2;  // 4.19 MB
  const size_t o_V   = o_K + (size_t)Bd * NKV * Td * HD * 2; // 4.19 MB
  const size_t o_woT = o_V + (size_t)Bd * NKV * HD * Td * 2; // 8.39 MB (fused path)
  const size_t need  = o_woT + (size_t)Cd * Cd * 2;

  bf16* xb  = (bf16*)(ws + o_xb);
  bf16* w1  = (bf16*)(ws + o_w1);
  bf16* Qb  = (bf16*)(ws + o_Q);
  bf16* Kb  = (bf16*)(ws + o_K);
  bf16* Vtb = (bf16*)(ws + o_V);
  bf16* yb  = xb;   // alias: x_bf16 dead after QKV GEMM

  bool fused = (ws_size >= need);
  bf16* woT = fused ? (bf16*)(ws + o_woT) : w1;

  // 1. prep1: x->bf16 + wq/wk/wv (+wo if ws allows) transposes
  prep1_kernel<<<dim3(fused ? 18432 : 14336), dim3(256), 0, stream>>>(
      x, wq, wk, wv, wo, xb, w1, woT);
  // 2. fused QKV projection (N = 3072) with in-epilogue RoPE; 256x192 tiles
  gemm_qkv<<<dim3(Md / 256, 3072 / 192), dim3(512), 0, stream>>>(xb, w1, Qb, Md, 3072, Cd);
  // 3. (fallback only) wo transpose into w1
  if (!fused)
    transpose_f2b<<<dim3(Cd / 32, Cd / 32), dim3(256), 0, stream>>>(wo, w1, Cd, Cd);
  // 4. attention -> yb (bf16 [M][C]); 8-wave LDS-staged blocks, LPT order
  attn_kernel<<<dim3(Bd * NH, 8), dim3(512), 0, stream>>>(Qb, Kb, Vtb, yb);
  // 5. output projection -> d_out (fp32); 256x128 tiles, full-chip grid
  gemm_out<<<dim3(Md / 256, Cd / 128), dim3(512), 0, stream>>>(yb, woT, (float*)d_out, Md, Cd, Cd);
}